// Round 7
// baseline (142.354 us; speedup 1.0000x reference)
//
#include <hip/hip_runtime.h>
#include <math.h>

#define BATCH 2048
#define FEAT  2048
#define LUTSZ 64

// ---------------------------------------------------------------------------
// Round-7 = round-6 structure + the race fix.
//
// Round-6 bug: barrier-free intra-wave LDS redistribution. Per-thread alias
// analysis proves reads srw2[3l+1], srw2[3l+2] never alias the SAME thread's
// writes srw2[l], srw2[64+l], srw2[128+l] (no lane solves 24l+8==8l+512 etc.),
// and cross-lane visibility is a data race in the SIMT memory model -> the
// backend hoisted the ds_reads above the ds_writes -> ~all outputs wrong
// (absmax 7.08 == max of millions of wrong-LUT diffs).
//
// Fix: __builtin_amdgcn_sched_barrier(0) + wave_barrier() around the
// write->read hand-off. Zero runtime cost; the DS pipe is in-order per wave,
// so fencing the COMPILER is sufficient; lgkmcnt on read results is
// compiler-inserted as usual.
//
// Numerics (locked, absmax 0.0 in rounds 4-5): f32 chain --
//   layer1 transform: (v + 1.0f) * 0.5f
//   sigmoid:          e = (float)exp(-(double)v);  s = 1.0f / (1.0f + e)
// hoisted into slut1/2 = sigmoid(lut1/2) precompute (bit-identical: same
// chain applied per (f, idx) instead of per (b, f)).
// ---------------------------------------------------------------------------

__device__ __forceinline__ void wave_fence() {
    __builtin_amdgcn_sched_barrier(0);
    __builtin_amdgcn_wave_barrier();
    __builtin_amdgcn_sched_barrier(0);
}

__global__ __launch_bounds__(256) void sigmoid_lut_kernel(
    const float* __restrict__ lut1, const float* __restrict__ lut2,
    float* __restrict__ slut1, float* __restrict__ slut2)
{
    const int n = FEAT * LUTSZ;
    int i = blockIdx.x * 256 + threadIdx.x;
    if (i < n) {
        float v = lut1[i];
        float e = (float)exp(-(double)v);     // correctly-rounded f32 exp
        slut1[i] = 1.0f / (1.0f + e);         // f32 IEEE chain (matches np)
    } else {
        i -= n;
        float v = lut2[i];
        float e = (float)exp(-(double)v);
        slut2[i] = 1.0f / (1.0f + e);
    }
}

template<int TO_GLOBAL>
__device__ __forceinline__ void lut_layer(
    const float* __restrict__ r, const int* __restrict__ c,
    const float* __restrict__ lut,        // slut (layers 1-2) or lut3
    const float* xsrc,                    // LDS source activation row
    float* ydst,                          // LDS dest row (TO_GLOBAL=0)
    float* __restrict__ outg,             // global dest (TO_GLOBAL=1)
    float* srw, int* siw,                 // wave-private scratch, 384 elems
    int b, int lane, int w)
{
    float2* srw2 = reinterpret_cast<float2*>(srw);
    int2*   siw2 = reinterpret_cast<int2*>(siw);

    #pragma unroll 2
    for (int k = 0; k < 8; ++k) {
        const int fw = k * 256 + w * 64;   // wave's base feature

        // Fully-coalesced loads of the wave's 64-feature r/c slice (1536 B).
        const float2* rg = reinterpret_cast<const float2*>(
            r + ((size_t)b * FEAT + fw) * 6);
        const int2* cg = reinterpret_cast<const int2*>(c + (size_t)fw * 6);
        const float2 ra = rg[lane], rb = rg[64 + lane], rc = rg[128 + lane];
        const int2   ca = cg[lane], cb = cg[64 + lane], cc = cg[128 + lane];

        // --- intra-wave exchange: fence BOTH sides so the compiler can't
        // hoist this iteration's writes above the previous iteration's reads,
        // nor the reads below above these writes. ---
        wave_fence();
        srw2[lane] = ra; srw2[64 + lane] = rb; srw2[128 + lane] = rc;
        siw2[lane] = ca; siw2[64 + lane] = cb; siw2[128 + lane] = cc;
        wave_fence();

        const float2 q0 = srw2[lane * 3 + 0];
        const float2 q1 = srw2[lane * 3 + 1];
        const float2 q2 = srw2[lane * 3 + 2];
        const int2   d0 = siw2[lane * 3 + 0];
        const int2   d1 = siw2[lane * 3 + 1];
        const int2   d2 = siw2[lane * 3 + 2];

        int idx = 0;
        idx |= (xsrc[d0.x] >= q0.x) ? 1  : 0;
        idx |= (xsrc[d0.y] >= q0.y) ? 2  : 0;
        idx |= (xsrc[d1.x] >= q1.x) ? 4  : 0;
        idx |= (xsrc[d1.y] >= q1.y) ? 8  : 0;
        idx |= (xsrc[d2.x] >= q2.x) ? 16 : 0;
        idx |= (xsrc[d2.y] >= q2.y) ? 32 : 0;

        const int f = fw + lane;
        const float v = lut[(size_t)f * LUTSZ + idx];
        if (TO_GLOBAL) outg[(size_t)b * FEAT + f] = v;
        else           ydst[f] = v;
    }
}

__global__ __launch_bounds__(256) void fused3_kernel(
    const float* __restrict__ inputs,
    const float* __restrict__ r1, const float* __restrict__ r2,
    const float* __restrict__ r3,
    const float* __restrict__ slut1, const float* __restrict__ slut2,
    const float* __restrict__ lut3,
    const int* __restrict__ c1, const int* __restrict__ c2,
    const int* __restrict__ c3,
    float* __restrict__ out)
{
    __shared__ float xs[FEAT];          // 8 KiB
    __shared__ float ys[FEAT];          // 8 KiB
    __shared__ float sr[4 * 384];       // 6 KiB  wave-private r scratch
    __shared__ int   si[4 * 384];       // 6 KiB  wave-private c scratch
                                        // 28 KiB total -> 5 blocks/CU

    const int b    = blockIdx.x;
    const int tid  = threadIdx.x;
    const int lane = tid & 63;
    const int w    = tid >> 6;

    // Stage input row -> xs with the exact f32 transform (v+1.0f)*0.5f.
    {
        const float4* xrow = reinterpret_cast<const float4*>(
            inputs + (size_t)b * FEAT);
        float4* xs4 = reinterpret_cast<float4*>(xs);
        #pragma unroll
        for (int i = tid; i < FEAT / 4; i += 256) {
            float4 v = xrow[i];
            v.x = (v.x + 1.0f) * 0.5f;
            v.y = (v.y + 1.0f) * 0.5f;
            v.z = (v.z + 1.0f) * 0.5f;
            v.w = (v.w + 1.0f) * 0.5f;
            xs4[i] = v;
        }
    }
    __syncthreads();

    float* srw = sr + w * 384;
    int*   siw = si + w * 384;

    lut_layer<0>(r1, c1, slut1, xs, ys, nullptr, srw, siw, b, lane, w);
    __syncthreads();
    lut_layer<0>(r2, c2, slut2, ys, xs, nullptr, srw, siw, b, lane, w);
    __syncthreads();
    lut_layer<1>(r3, c3, lut3, xs, nullptr, out, srw, siw, b, lane, w);
}

extern "C" void kernel_launch(void* const* d_in, const int* in_sizes, int n_in,
                              void* d_out, int out_size, void* d_ws, size_t ws_size,
                              hipStream_t stream) {
    const float* inputs = (const float*)d_in[0];
    const float* r1     = (const float*)d_in[1];
    const float* r2     = (const float*)d_in[2];
    const float* r3     = (const float*)d_in[3];
    const float* lut1   = (const float*)d_in[4];
    const float* lut2   = (const float*)d_in[5];
    const float* lut3   = (const float*)d_in[6];
    const int*   c1     = (const int*)d_in[7];
    const int*   c2     = (const int*)d_in[8];
    const int*   c3     = (const int*)d_in[9];
    float* out = (float*)d_out;

    float* slut1 = (float*)d_ws;                       // [FEAT, 64]
    float* slut2 = slut1 + (size_t)FEAT * LUTSZ;       // [FEAT, 64]

    // Prologue: precompute sigmoid(lut1/2) with the exact f32 chain.
    sigmoid_lut_kernel<<<dim3(2 * FEAT * LUTSZ / 256), dim3(256), 0, stream>>>(
        lut1, lut2, slut1, slut2);

    fused3_kernel<<<dim3(BATCH), dim3(256), 0, stream>>>(
        inputs, r1, r2, r3, slut1, slut2, lut3, c1, c2, c3, out);
}

// Round 8
// 135.386 us; speedup vs baseline: 1.0515x; 1.0515x over previous
//
#include <hip/hip_runtime.h>
#include <math.h>

#define BATCH 2048
#define FEAT  2048
#define LUTSZ 64

// ---------------------------------------------------------------------------
// Round-8 = round-7 (passing, absmax 0.0) + depth-2 software pipeline.
//
// r7 diagnosis: per-iter serial chain (HBM load latency + fence walls +
// exchange + divergent slut gather) ~1.5K cyc x 24 iters, ~4 waves/SIMD ->
// latency-bound at 175us with every pipe <15% busy.
//
// Changes:
//  * r/c chunk k+2 prefetched into registers 2 iters early (depth-2) -> the
//    vmcnt wait before the exchange ds_write hits data issued ~2 iters ago.
//  * exchange scratch double-buffered by k&1.
//  * layer barriers = "s_waitcnt lgkmcnt(0); s_barrier" so prefetched
//    NEXT-LAYER loads stay in flight across the barrier (only read-only
//    global r/c is outstanding -> safe; LDS ys writes are drained).
//  * numerics/exchange discipline identical to r7 (fences + in-order DS).
// ---------------------------------------------------------------------------

struct RC { float2 r0, r1, r2; int2 c0, c1, c2; };

__device__ __forceinline__ void wave_fence() {
    __builtin_amdgcn_sched_barrier(0);
    __builtin_amdgcn_wave_barrier();
    __builtin_amdgcn_sched_barrier(0);
}

// Block barrier that drains LDS but leaves vmem loads in flight.
__device__ __forceinline__ void block_sync_keep_vm() {
    __builtin_amdgcn_sched_barrier(0);
    asm volatile("s_waitcnt lgkmcnt(0)\n\ts_barrier" ::: "memory");
    __builtin_amdgcn_sched_barrier(0);
}

__device__ __forceinline__ RC load_rc(const float* __restrict__ r,
                                      const int* __restrict__ c,
                                      int b, int fw, int lane) {
    const float2* rg = reinterpret_cast<const float2*>(
        r + ((size_t)b * FEAT + fw) * 6);
    const int2* cg = reinterpret_cast<const int2*>(c + (size_t)fw * 6);
    RC x;
    x.r0 = rg[lane]; x.r1 = rg[64 + lane]; x.r2 = rg[128 + lane];
    x.c0 = cg[lane]; x.c1 = cg[64 + lane]; x.c2 = cg[128 + lane];
    return x;
}

__global__ __launch_bounds__(256) void sigmoid_lut_kernel(
    const float* __restrict__ lut1, const float* __restrict__ lut2,
    float* __restrict__ slut1, float* __restrict__ slut2)
{
    const int n = FEAT * LUTSZ;
    int i = blockIdx.x * 256 + threadIdx.x;
    if (i < n) {
        float v = lut1[i];
        float e = (float)exp(-(double)v);     // correctly-rounded f32 exp
        slut1[i] = 1.0f / (1.0f + e);         // f32 IEEE chain (matches np)
    } else {
        i -= n;
        float v = lut2[i];
        float e = (float)exp(-(double)v);
        slut2[i] = 1.0f / (1.0f + e);
    }
}

// a  = data for chunk k   (in regs)
// b_ = data for chunk k+1 (in regs)
// On exit (LAST=false): a,b_ hold the NEXT layer's chunks 0,1.
template<int TO_GLOBAL, bool LAST>
__device__ __forceinline__ void layer_run(
    RC& a, RC& b_,
    const float* __restrict__ rcur, const int* __restrict__ ccur,
    const float* __restrict__ rnxt, const int* __restrict__ cnxt,
    const float* __restrict__ lut,
    const float* xsrc, float* ydst, float* __restrict__ outg,
    float2 (*sr)[192], int2 (*si)[192],    // this wave's 2 scratch buffers
    int b, int lane, int w)
{
    #pragma unroll
    for (int k = 0; k < 8; ++k) {
        float2* srw = sr[k & 1];
        int2*   siw = si[k & 1];

        // ---- exchange write (waits vmcnt for loads issued 2 iters ago) ----
        wave_fence();
        srw[lane] = a.r0; srw[64 + lane] = a.r1; srw[128 + lane] = a.r2;
        siw[lane] = a.c0; siw[64 + lane] = a.c1; siw[128 + lane] = a.c2;
        wave_fence();

        // ---- prefetch chunk k+2 (crosses into next layer at k>=6) ----
        RC n;
        if (k < 6) {
            n = load_rc(rcur, ccur, b, ((k + 2) & 7) * 256 + w * 64, lane);
        } else if (!LAST) {
            n = load_rc(rnxt, cnxt, b, ((k + 2) & 7) * 256 + w * 64, lane);
        }

        // ---- compute chunk k from scratch ----
        const float2 q0 = srw[3 * lane + 0];
        const float2 q1 = srw[3 * lane + 1];
        const float2 q2 = srw[3 * lane + 2];
        const int2   d0 = siw[3 * lane + 0];
        const int2   d1 = siw[3 * lane + 1];
        const int2   d2 = siw[3 * lane + 2];

        int idx = 0;
        idx |= (xsrc[d0.x] >= q0.x) ? 1  : 0;
        idx |= (xsrc[d0.y] >= q0.y) ? 2  : 0;
        idx |= (xsrc[d1.x] >= q1.x) ? 4  : 0;
        idx |= (xsrc[d1.y] >= q1.y) ? 8  : 0;
        idx |= (xsrc[d2.x] >= q2.x) ? 16 : 0;
        idx |= (xsrc[d2.y] >= q2.y) ? 32 : 0;

        const int f = k * 256 + w * 64 + lane;
        const float v = lut[(size_t)f * LUTSZ + idx];
        if (TO_GLOBAL) outg[(size_t)b * FEAT + f] = v;
        else           ydst[f] = v;

        // ---- rotate registers ----
        a = b_;
        if (!(LAST && k >= 6)) b_ = n;
    }
}

__global__ __launch_bounds__(256) void fused3_pipe(
    const float* __restrict__ inputs,
    const float* __restrict__ r1, const float* __restrict__ r2,
    const float* __restrict__ r3,
    const float* __restrict__ slut1, const float* __restrict__ slut2,
    const float* __restrict__ lut3,
    const int* __restrict__ c1, const int* __restrict__ c2,
    const int* __restrict__ c3,
    float* __restrict__ out)
{
    __shared__ float  xs[FEAT];        // 8 KiB
    __shared__ float  ys[FEAT];        // 8 KiB
    __shared__ float2 sr[4][2][192];   // 12 KiB  wave x dbuf r-scratch
    __shared__ int2   si[4][2][192];   // 12 KiB  wave x dbuf c-scratch
                                       // 40 KiB total -> 4 blocks/CU

    const int b    = blockIdx.x;
    const int tid  = threadIdx.x;
    const int lane = tid & 63;
    const int w    = tid >> 6;

    // Prefetch layer-1 chunks 0,1 FIRST (latency hides under xs staging).
    RC a  = load_rc(r1, c1, b, 0 * 256 + w * 64, lane);
    RC b_ = load_rc(r1, c1, b, 1 * 256 + w * 64, lane);

    // Stage input row -> xs with the exact f32 transform (v+1.0f)*0.5f.
    {
        const float4* xrow = reinterpret_cast<const float4*>(
            inputs + (size_t)b * FEAT);
        float4* xs4 = reinterpret_cast<float4*>(xs);
        #pragma unroll
        for (int i = tid; i < FEAT / 4; i += 256) {
            float4 v = xrow[i];
            v.x = (v.x + 1.0f) * 0.5f;
            v.y = (v.y + 1.0f) * 0.5f;
            v.z = (v.z + 1.0f) * 0.5f;
            v.w = (v.w + 1.0f) * 0.5f;
            xs4[i] = v;
        }
    }
    block_sync_keep_vm();

    layer_run<0, false>(a, b_, r1, c1, r2, c2, slut1, xs, ys, nullptr,
                        sr[w], si[w], b, lane, w);
    block_sync_keep_vm();
    layer_run<0, false>(a, b_, r2, c2, r3, c3, slut2, ys, xs, nullptr,
                        sr[w], si[w], b, lane, w);
    block_sync_keep_vm();
    layer_run<1, true>(a, b_, r3, c3, r3, c3, lut3, xs, nullptr, out,
                       sr[w], si[w], b, lane, w);
}

extern "C" void kernel_launch(void* const* d_in, const int* in_sizes, int n_in,
                              void* d_out, int out_size, void* d_ws, size_t ws_size,
                              hipStream_t stream) {
    const float* inputs = (const float*)d_in[0];
    const float* r1     = (const float*)d_in[1];
    const float* r2     = (const float*)d_in[2];
    const float* r3     = (const float*)d_in[3];
    const float* lut1   = (const float*)d_in[4];
    const float* lut2   = (const float*)d_in[5];
    const float* lut3   = (const float*)d_in[6];
    const int*   c1     = (const int*)d_in[7];
    const int*   c2     = (const int*)d_in[8];
    const int*   c3     = (const int*)d_in[9];
    float* out = (float*)d_out;

    float* slut1 = (float*)d_ws;                       // [FEAT, 64]
    float* slut2 = slut1 + (size_t)FEAT * LUTSZ;       // [FEAT, 64]

    sigmoid_lut_kernel<<<dim3(2 * FEAT * LUTSZ / 256), dim3(256), 0, stream>>>(
        lut1, lut2, slut1, slut2);

    fused3_pipe<<<dim3(BATCH), dim3(256), 0, stream>>>(
        inputs, r1, r2, r3, slut1, slut2, lut3, c1, c2, c3, out);
}

// Round 9
// 131.563 us; speedup vs baseline: 1.0820x; 1.0291x over previous
//
#include <hip/hip_runtime.h>
#include <math.h>

#define BATCH 2048
#define FEAT  2048
#define LUTSZ 64

// ---------------------------------------------------------------------------
// Round-9: ballot-transpose — the r/c LDS exchange is eliminated.
//
// Per wave, chunk k covers 64 features (fw..fw+63) = 384 r-floats / c-ints.
// Coalesced float2/int2 loads put element e of the slice in lane (e&127)>>1,
// register group e>>7, half e&1 (a scrambled but FIXED permutation).
// Instead of un-scrambling 24 B/lane through LDS scratch (the r5-r8 exchange,
// ~140 LDS-pipe cyc/iter), each lane compares IN the scrambled layout:
//     pred = xs[c_e] >= r_e
// and the 1-bit results are redistributed by __ballot (free: v_cmp -> sgpr).
// Owner lane phi extracts bits e = 6*phi + j from ballot B[2*(e>>7)+(e&1)]
// at position (e&127)>>1 -- ~70 VALU ops/iter, VALU is 5% busy.
//
// Same comparisons, same operands, pure permutation => bit-identical output
// (absmax 0.0 chain preserved: slut = 1/(1+RN32(exp_f64(-lut))) precomputed;
// layer-1 transform (v+1.0f)*0.5f).
//
// No wave-shared scratch left -> no fences -> compiler free to overlap
// iterations; depth-2 register prefetch of r/c retained (r8, proven).
// LDS = xs+ys = 16 KiB only.
// ---------------------------------------------------------------------------

struct RC { float2 r0, r1, r2; int2 c0, c1, c2; };

// Block barrier that drains LDS but leaves (read-only) vmem loads in flight.
__device__ __forceinline__ void block_sync_keep_vm() {
    __builtin_amdgcn_sched_barrier(0);
    asm volatile("s_waitcnt lgkmcnt(0)\n\ts_barrier" ::: "memory");
    __builtin_amdgcn_sched_barrier(0);
}

__device__ __forceinline__ RC load_rc(const float* __restrict__ r,
                                      const int* __restrict__ c,
                                      int b, int fw, int lane) {
    const float2* rg = reinterpret_cast<const float2*>(
        r + ((size_t)b * FEAT + fw) * 6);
    const int2* cg = reinterpret_cast<const int2*>(c + (size_t)fw * 6);
    RC x;
    x.r0 = rg[lane]; x.r1 = rg[64 + lane]; x.r2 = rg[128 + lane];
    x.c0 = cg[lane]; x.c1 = cg[64 + lane]; x.c2 = cg[128 + lane];
    return x;
}

__global__ __launch_bounds__(256) void sigmoid_lut_kernel(
    const float* __restrict__ lut1, const float* __restrict__ lut2,
    float* __restrict__ slut1, float* __restrict__ slut2)
{
    const int n = FEAT * LUTSZ;
    int i = blockIdx.x * 256 + threadIdx.x;
    if (i < n) {
        float v = lut1[i];
        float e = (float)exp(-(double)v);     // correctly-rounded f32 exp
        slut1[i] = 1.0f / (1.0f + e);         // f32 IEEE chain (matches np)
    } else {
        i -= n;
        float v = lut2[i];
        float e = (float)exp(-(double)v);
        slut2[i] = 1.0f / (1.0f + e);
    }
}

// a = chunk k data, b_ = chunk k+1 data (registers, scrambled layout).
// On exit (LAST=false): a,b_ hold the NEXT layer's chunks 0,1.
template<int TO_GLOBAL, bool LAST>
__device__ __forceinline__ void layer_run(
    RC& a, RC& b_,
    const float* __restrict__ rcur, const int* __restrict__ ccur,
    const float* __restrict__ rnxt, const int* __restrict__ cnxt,
    const float* __restrict__ lut,
    const float* xsrc, float* ydst, float* __restrict__ outg,
    int b, int lane, int w)
{
    #pragma unroll
    for (int k = 0; k < 8; ++k) {
        // ---- prefetch chunk k+2 (crosses into next layer at k>=6) ----
        RC n;
        if (k < 6) {
            n = load_rc(rcur, ccur, b, ((k + 2) & 7) * 256 + w * 64, lane);
        } else if (!LAST) {
            n = load_rc(rnxt, cnxt, b, ((k + 2) & 7) * 256 + w * 64, lane);
        }

        // ---- compare in scrambled layout; redistribute bits via ballot ----
        // lane l holds slice elements {2l, 2l+1, 2l+128, 2l+129, 2l+256, 2l+257}
        const unsigned long long B0 = __ballot(xsrc[a.c0.x] >= a.r0.x);
        const unsigned long long B1 = __ballot(xsrc[a.c0.y] >= a.r0.y);
        const unsigned long long B2 = __ballot(xsrc[a.c1.x] >= a.r1.x);
        const unsigned long long B3 = __ballot(xsrc[a.c1.y] >= a.r1.y);
        const unsigned long long B4 = __ballot(xsrc[a.c2.x] >= a.r2.x);
        const unsigned long long B5 = __ballot(xsrc[a.c2.y] >= a.r2.y);

        // owner lane phi needs elements e = 6*phi + j, j=0..5:
        //   ballot index 2*(e>>7) + (e&1), bit position (e&127)>>1
        int idx = 0;
        #pragma unroll
        for (int j = 0; j < 6; ++j) {
            const int e = 6 * lane + j;          // 6*lane even => e&1 == j&1
            const int g = e >> 7;                // 0,1,2 (per-lane)
            const unsigned long long src =
                (j & 1) ? ((g == 0) ? B1 : (g == 1) ? B3 : B5)
                        : ((g == 0) ? B0 : (g == 1) ? B2 : B4);
            idx |= (int)((src >> ((e & 127) >> 1)) & 1ull) << j;
        }

        const int f = k * 256 + w * 64 + lane;
        const float v = lut[(size_t)f * LUTSZ + idx];
        if (TO_GLOBAL) outg[(size_t)b * FEAT + f] = v;
        else           ydst[f] = v;

        // ---- rotate prefetch registers ----
        a = b_;
        if (!(LAST && k >= 6)) b_ = n;
    }
}

__global__ __launch_bounds__(256) void fused3_ballot(
    const float* __restrict__ inputs,
    const float* __restrict__ r1, const float* __restrict__ r2,
    const float* __restrict__ r3,
    const float* __restrict__ slut1, const float* __restrict__ slut2,
    const float* __restrict__ lut3,
    const int* __restrict__ c1, const int* __restrict__ c2,
    const int* __restrict__ c3,
    float* __restrict__ out)
{
    __shared__ float xs[FEAT];   // 8 KiB
    __shared__ float ys[FEAT];   // 8 KiB   -> 16 KiB total

    const int b    = blockIdx.x;
    const int tid  = threadIdx.x;
    const int lane = tid & 63;
    const int w    = tid >> 6;

    // Prefetch layer-1 chunks 0,1 first (latency hides under xs staging).
    RC a  = load_rc(r1, c1, b, 0 * 256 + w * 64, lane);
    RC b_ = load_rc(r1, c1, b, 1 * 256 + w * 64, lane);

    // Stage input row -> xs with the exact f32 transform (v+1.0f)*0.5f.
    {
        const float4* xrow = reinterpret_cast<const float4*>(
            inputs + (size_t)b * FEAT);
        float4* xs4 = reinterpret_cast<float4*>(xs);
        #pragma unroll
        for (int i = tid; i < FEAT / 4; i += 256) {
            float4 v = xrow[i];
            v.x = (v.x + 1.0f) * 0.5f;
            v.y = (v.y + 1.0f) * 0.5f;
            v.z = (v.z + 1.0f) * 0.5f;
            v.w = (v.w + 1.0f) * 0.5f;
            xs4[i] = v;
        }
    }
    block_sync_keep_vm();

    layer_run<0, false>(a, b_, r1, c1, r2, c2, slut1, xs, ys, nullptr,
                        b, lane, w);
    block_sync_keep_vm();
    layer_run<0, false>(a, b_, r2, c2, r3, c3, slut2, ys, xs, nullptr,
                        b, lane, w);
    block_sync_keep_vm();
    layer_run<1, true>(a, b_, r3, c3, r3, c3, lut3, xs, nullptr, out,
                       b, lane, w);
}

extern "C" void kernel_launch(void* const* d_in, const int* in_sizes, int n_in,
                              void* d_out, int out_size, void* d_ws, size_t ws_size,
                              hipStream_t stream) {
    const float* inputs = (const float*)d_in[0];
    const float* r1     = (const float*)d_in[1];
    const float* r2     = (const float*)d_in[2];
    const float* r3     = (const float*)d_in[3];
    const float* lut1   = (const float*)d_in[4];
    const float* lut2   = (const float*)d_in[5];
    const float* lut3   = (const float*)d_in[6];
    const int*   c1     = (const int*)d_in[7];
    const int*   c2     = (const int*)d_in[8];
    const int*   c3     = (const int*)d_in[9];
    float* out = (float*)d_out;

    float* slut1 = (float*)d_ws;                       // [FEAT, 64]
    float* slut2 = slut1 + (size_t)FEAT * LUTSZ;       // [FEAT, 64]

    sigmoid_lut_kernel<<<dim3(2 * FEAT * LUTSZ / 256), dim3(256), 0, stream>>>(
        lut1, lut2, slut1, slut2);

    fused3_ballot<<<dim3(BATCH), dim3(256), 0, stream>>>(
        inputs, r1, r2, r3, slut1, slut2, lut3, c1, c2, c3, out);
}